// Round 15
// baseline (544.653 us; speedup 1.0000x reference)
//
#include <hip/hip_runtime.h>
#include <hip/hip_bf16.h>
#include <math.h>

// GRU decoder, fused v2: embed+relu -> gi GEMM -> MEGA {8 elected blocks: GRU
// recurrence (t-major HS, LLC flags); 248 blocks: per-XCD nt-queues, cast-on-claim
// Wout panel, 3-group 128^2 proj tiles gated on GRU progress} -> log_softmax.

typedef __bf16 bf16x8 __attribute__((ext_vector_type(8)));
typedef float  f32x4  __attribute__((ext_vector_type(4)));
typedef unsigned short u16;
typedef u16 u16x8v __attribute__((ext_vector_type(8)));
typedef u16 u16x4v __attribute__((ext_vector_type(4)));

#define BTV (32L * 64 * 32000)
#define LDC2 64000L   // bf16 logit row stride inside d_out (half of a 128000B f32 row slot)

// ---- ws layout (bytes) ----
#define OFF_X    (0L)
#define SZ_X     (2048L * 256 * 2)
#define OFF_WIH  (OFF_X + SZ_X)
#define SZ_WIH   (1536L * 256 * 2)
#define OFF_WHH  (OFF_WIH + SZ_WIH)
#define SZ_WHH   (1536L * 512 * 2)
#define OFF_WOUT (OFF_WHH + SZ_WHH)
#define SZ_WOUT  (32000L * 512 * 2)
#define OFF_GI   (OFF_WOUT + SZ_WOUT)
#define SZ_GI    (2048L * 1536 * 4)
#define OFF_HS   (OFF_GI + SZ_GI)
#define SZ_HS    (2048L * 512 * 2)
#define OFF_FLG  (OFF_HS + SZ_HS)
#define SZ_FLG   (1024L)
#define OFF_EV   (OFF_FLG + SZ_FLG)
#define SZ_EV    (128L)
#define WS_NEED  (OFF_EV + SZ_EV)

__device__ __forceinline__ u16 f2bf(float f) {
  union { float f; unsigned u; } a; a.f = f;
  unsigned r = a.u + 0x7fffu + ((a.u >> 16) & 1u);
  return (u16)(r >> 16);
}

__device__ __forceinline__ float bf2f(u16 u) {
  union { unsigned u; float f; } a; a.u = ((unsigned)u) << 16;
  return a.f;
}

__device__ __forceinline__ void gload16(const void* g, void* l) {
  __builtin_amdgcn_global_load_lds(
      (const __attribute__((address_space(1))) unsigned int*)g,
      (__attribute__((address_space(3))) unsigned int*)l, 16, 0, 0);
}

// ---------------- cast f32 -> bf16 ----------------
extern "C" __global__ void k_cast(const float* __restrict__ s, u16* __restrict__ d, int n4) {
  int i = blockIdx.x * blockDim.x + threadIdx.x;
  int st = gridDim.x * blockDim.x;
  for (; i < n4; i += st) {
    float4 v = reinterpret_cast<const float4*>(s)[i];
    u16x4v o; o.x = f2bf(v.x); o.y = f2bf(v.y); o.z = f2bf(v.z); o.w = f2bf(v.w);
    reinterpret_cast<u16x4v*>(d)[i] = o;
  }
}

// ---------------- embed + relu -> X[t*32+b][256] bf16 ----------------
extern "C" __global__ void k_embed(const float* __restrict__ emb, const int* __restrict__ tgt,
                                   u16* __restrict__ X) {
  int idx = blockIdx.x * 256 + threadIdx.x;
  int row = idx >> 5;
  int c8  = (idx & 31) << 3;
  int t = row >> 5, b = row & 31;
  int token = (t == 0) ? 0 : tgt[b * 64 + t - 1];
  const float* e = emb + (long)token * 256 + c8;
  u16x8v o;
#pragma unroll
  for (int i = 0; i < 8; ++i) { float v = e[i]; o[i] = f2bf(v > 0.f ? v : 0.f); }
  *reinterpret_cast<u16x8v*>(X + (long)row * 256 + c8) = o;
}

// ---------------- flags + election/queue vars init ----------------
extern "C" __global__ void k_init(unsigned* flags, unsigned* evars) {
  int i = threadIdx.x;
  if (i < 256) {
    unsigned z = 0u;
    asm volatile("global_store_dword %0, %1, off sc0 sc1"
                 :: "v"(flags + i), "v"(z) : "memory");
  }
  if (i < 32) atomicExch(&evars[i], i == 8 ? 0xFFFFFFFFu : 0u);
}

// ---------------- gi GEMM: C = A*B^T + bias (f32 out), 2-phase dbuf, XCD-affine ----------------
extern "C" __global__ void __launch_bounds__(256)
k_gemm_gi(const u16* __restrict__ A, const u16* __restrict__ B,
          const float* __restrict__ bias, float* __restrict__ C,
          int M, int N, int K) {
  __shared__ u16 At[2][4096];
  __shared__ u16 Bt[2][4096];
  int mt = M >> 7;
  int i = blockIdx.x;
  int j = (i & 7) * ((int)gridDim.x >> 3) + (i >> 3);
  int bn = j / mt, bm = j % mt;
  int tid = threadIdx.x, wave = tid >> 6, lane = tid & 63;
  int wr = wave >> 1, wc = wave & 1;
  f32x4 acc[4][4] = {};
  const u16* ga = A + (long)(bm * 128 + wave * 32 + (lane >> 2)) * K + ((lane & 3) << 3);
  const u16* gb = B + (long)(bn * 128 + wave * 32 + (lane >> 2)) * K + ((lane & 3) << 3);
  long k16 = 16L * K;
  {
    u16* la0 = &At[0][wave * 1024]; u16* lb0 = &Bt[0][wave * 1024];
    gload16(ga, la0); gload16(ga + k16, la0 + 512);
    gload16(gb, lb0); gload16(gb + k16, lb0 + 512);
  }
  asm volatile("s_waitcnt vmcnt(0)" ::: "memory");
  __syncthreads();
  int cur = 0;
  for (int k0 = 0; k0 < K; k0 += 32) {
    if (k0 + 32 < K) {
      int nb = cur ^ 1;
      u16* la0 = &At[nb][wave * 1024]; u16* lb0 = &Bt[nb][wave * 1024];
      gload16(ga + k0 + 32, la0); gload16(ga + k16 + k0 + 32, la0 + 512);
      gload16(gb + k0 + 32, lb0); gload16(gb + k16 + k0 + 32, lb0 + 512);
    }
    bf16x8 af[4], bfr[4];
#pragma unroll
    for (int mi = 0; mi < 4; ++mi)
      af[mi] = *reinterpret_cast<const bf16x8*>(
          &At[cur][(wr * 64 + mi * 16 + (lane & 15)) * 32 + ((lane >> 4) << 3)]);
#pragma unroll
    for (int ni = 0; ni < 4; ++ni)
      bfr[ni] = *reinterpret_cast<const bf16x8*>(
          &Bt[cur][(wc * 64 + ni * 16 + (lane & 15)) * 32 + ((lane >> 4) << 3)]);
#pragma unroll
    for (int mi = 0; mi < 4; ++mi)
#pragma unroll
      for (int ni = 0; ni < 4; ++ni)
        acc[mi][ni] = __builtin_amdgcn_mfma_f32_16x16x32_bf16(af[mi], bfr[ni], acc[mi][ni], 0, 0, 0);
    asm volatile("s_waitcnt vmcnt(0)" ::: "memory");
    __syncthreads();
    cur ^= 1;
  }
  int rb = bm * 128 + wr * 64 + ((lane >> 4) << 2);
  int cb = bn * 128 + wc * 64 + (lane & 15);
#pragma unroll
  for (int mi = 0; mi < 4; ++mi)
#pragma unroll
    for (int ni = 0; ni < 4; ++ni) {
      int col = cb + ni * 16;
      float bv = bias[col];
#pragma unroll
      for (int q = 0; q < 4; ++q) {
        int rr = rb + mi * 16 + q;
        C[(long)rr * N + col] = acc[mi][ni][q] + bv;
      }
    }
}

// ---------------- MEGA v2: GRU (8 elected) + XCD-local streaming projection ----------------
// HS t-major (row = t*32+b). GRU: R12 body (fixed staging advance), W_hh loaded f32.
// Proj: per-XCD nt-queue; claim = one nt (cast 128-col Wout panel f32->bf16 once,
// then 16 mt-tiles in 6 poll-gated rounds of 3 via 3 wave-groups).
extern "C" __global__ void __launch_bounds__(768, 1)
k_mega2(const float* __restrict__ gi, const float* __restrict__ WhhF,
        const float* __restrict__ bhh, const float* __restrict__ eh,
        u16* __restrict__ HS, float* __restrict__ outH,
        unsigned* flags, unsigned* evars,
        const float* __restrict__ WoutF, u16* __restrict__ WoutB,
        const float* __restrict__ bout, u16* __restrict__ LG) {
  extern __shared__ char arena[];
  __shared__ int role_s;
  __shared__ int xcd_s;
  __shared__ int lead_s;
  __shared__ int tick_s;
  int tid = threadIdx.x, wave = tid >> 6, lane = tid & 63;
  if (tid == 0) {
    unsigned xcc;
    asm volatile("s_getreg_b32 %0, hwreg(20, 0, 32)" : "=s"(xcc));
    xcc &= 7u;
    unsigned arr = atomicAdd(&evars[xcc], 1u);
    if (arr == 7u) atomicCAS(&evars[8], 0xFFFFFFFFu, xcc);
    unsigned L = 0xFFFFFFFFu;
    for (int it = 0; it < (1 << 24) && L == 0xFFFFFFFFu; ++it) {
      asm volatile("global_load_dword %0, %1, off sc0 sc1\n\ts_waitcnt vmcnt(0)"
                   : "=v"(L) : "v"(evars + 8) : "memory");
    }
    int role = -1;
    if (L == xcc) {
      unsigned c = atomicAdd(&evars[9], 1u);
      if (c < 8u) role = (int)c;
    }
    role_s = role;
    xcd_s = (int)xcc;
    lead_s = (int)(L & 7u);
  }
  __syncthreads();
  int g = role_s;

  if (g >= 0) {
    // ================= GRU path (R12 body; barr from f32 W_hh) =================
    u16* Ah = (u16*)arena;                                           // 32 KB
    float (*gh)[2][32][66] = (float (*)[2][32][66])(arena + 32768);  // 50688 B
    int j0 = g * 64;
    int gate = wave >> 2, uh = (wave >> 1) & 1, sig = wave & 1;
    bf16x8 barr[2][8];
    {
      const float* wbase = WhhF + (long)(gate * 512 + j0 + uh * 32) * 512 + sig * 256;
#pragma unroll
      for (int ut = 0; ut < 2; ++ut)
#pragma unroll
        for (int kt = 0; kt < 8; ++kt) {
          const float* wp = wbase + (long)(ut * 16 + (lane & 15)) * 512 + kt * 32 + ((lane >> 4) << 3);
          float4 wa = *reinterpret_cast<const float4*>(wp);
          float4 wb = *reinterpret_cast<const float4*>(wp + 4);
          u16x8v o8;
          o8[0] = f2bf(wa.x); o8[1] = f2bf(wa.y); o8[2] = f2bf(wa.z); o8[3] = f2bf(wa.w);
          o8[4] = f2bf(wb.x); o8[5] = f2bf(wb.y); o8[6] = f2bf(wb.z); o8[7] = f2bf(wb.w);
          barr[ut][kt] = __builtin_bit_cast(bf16x8, o8);
        }
    }
    bool act2 = tid < 512;
    float hprev[3] = {}, bb0[3] = {}, bb1[3] = {}, bb2[3] = {};
    int b_[3], u_[3];
#pragma unroll
    for (int s = 0; s < 3; ++s) {
      int o = s * 768 + tid;
      if (o < 2048) {
        int b = o >> 6, u = o & 63, j = j0 + u;
        b_[s] = b; u_[s] = u;
        hprev[s] = eh[b * 512 + j];
        bb0[s] = bhh[j]; bb1[s] = bhh[512 + j]; bb2[s] = bhh[1024 + j];
      } else { b_[s] = 0; u_[s] = 0; }
    }
    const float* gp0 = gi + (long)b_[0] * 1536 + j0 + u_[0];
    const float* gp1 = gi + (long)b_[1] * 1536 + j0 + u_[1];
    const float* gp2 = act2 ? gi + (long)b_[2] * 1536 + j0 + u_[2] : nullptr;
    u16* hs0 = HS + (long)b_[0] * 512 + j0 + u_[0];
    u16* hs1 = HS + (long)b_[1] * 512 + j0 + u_[1];
    u16* hs2 = act2 ? HS + (long)b_[2] * 512 + j0 + u_[2] : nullptr;
    const char* sp0 = nullptr; const char* sp1 = nullptr;
    const char* sp2 = nullptr; const char* sp3 = nullptr;
    char* ld0 = nullptr; char* ld1 = nullptr; char* ld2 = nullptr; char* ld3 = nullptr;
    if (tid < 512) {
#pragma unroll
      for (int l = 0; l < 4; ++l) {
        int n = l * 512 + tid;
        int row = n >> 6, i = n & 63;
        char* ld = (char*)Ah + row * 1024 + ((i * 16) ^ ((row & 7) << 4));
        const char* sp = (const char*)HS + (long)n * 16 - 32768;
        if (l == 0) { sp0 = sp; ld0 = ld; } else if (l == 1) { sp1 = sp; ld1 = ld; }
        else if (l == 2) { sp2 = sp; ld2 = ld; } else { sp3 = sp; ld3 = ld; }
      }
#pragma unroll
      for (int l = 0; l < 4; ++l) {
        int n = l * 512 + tid;
        int row = n >> 6, i = n & 63;
        const float* p = eh + row * 512 + i * 8;
        float4 aa = *reinterpret_cast<const float4*>(p);
        float4 bb = *reinterpret_cast<const float4*>(p + 4);
        u16x8v o8;
        o8[0] = f2bf(aa.x); o8[1] = f2bf(aa.y); o8[2] = f2bf(aa.z); o8[3] = f2bf(aa.w);
        o8[4] = f2bf(bb.x); o8[5] = f2bf(bb.y); o8[6] = f2bf(bb.z); o8[7] = f2bf(bb.w);
        *reinterpret_cast<u16x8v*>((char*)Ah + row * 1024 + ((i * 16) ^ ((row & 7) << 4))) = o8;
      }
    }
    int r15 = lane & 15;
    int cbyte = sig * 512 + ((lane >> 4) << 4);
    int ucol = uh * 32 + r15;
    int brow = (lane >> 4) << 2;
    const float K1 = -1.44269504f, K2 = 2.88539009f;
    for (int t = 0; t < 64; ++t) {
      float gr0 = gp0[0], gz0 = gp0[512], gn0 = gp0[1024]; gp0 += 49152;
      float gr1 = gp1[0], gz1 = gp1[512], gn1 = gp1[1024]; gp1 += 49152;
      float gr2 = 0.f, gz2 = 0.f, gn2 = 0.f;
      if (act2) { gr2 = gp2[0]; gz2 = gp2[512]; gn2 = gp2[1024]; gp2 += 49152; }
      if (t) {
        if (wave == 0) {
          const unsigned* fp = flags + (lane & 7) * 16;
          unsigned v;
          do {
            asm volatile("global_load_dword %0, %1, off sc0 sc1\n\ts_waitcnt vmcnt(0)"
                         : "=v"(v) : "v"(fp) : "memory");
          } while (!__all((int)(v >= (unsigned)t)));
        }
        __syncthreads();
        if (tid < 512) {
          f32x4 d0, d1, d2, d3;
          asm volatile(
              "global_load_dwordx4 %0, %4, off sc0\n\t"
              "global_load_dwordx4 %1, %5, off sc0\n\t"
              "global_load_dwordx4 %2, %6, off sc0\n\t"
              "global_load_dwordx4 %3, %7, off sc0\n\t"
              "s_waitcnt vmcnt(0)"
              : "=v"(d0), "=v"(d1), "=v"(d2), "=v"(d3)
              : "v"(sp0), "v"(sp1), "v"(sp2), "v"(sp3)
              : "memory");
          *reinterpret_cast<f32x4*>(ld0) = d0;
          *reinterpret_cast<f32x4*>(ld1) = d1;
          *reinterpret_cast<f32x4*>(ld2) = d2;
          *reinterpret_cast<f32x4*>(ld3) = d3;
        }
      }
      // advance EVERY step (incl. t=0): step t reads step t-1's rows
      if (tid < 512) { sp0 += 32768; sp1 += 32768; sp2 += 32768; sp3 += 32768; }
      __syncthreads();   // Ah ready
      {
        f32x4 acc[2][2] = {};
#pragma unroll
        for (int kt = 0; kt < 8; ++kt) {
          bf16x8 a0 = *reinterpret_cast<const bf16x8*>(
              (const char*)Ah + r15 * 1024 + ((kt * 64 + cbyte) ^ ((r15 & 7) << 4)));
          bf16x8 a1 = *reinterpret_cast<const bf16x8*>(
              (const char*)Ah + (16 + r15) * 1024 + ((kt * 64 + cbyte) ^ ((r15 & 7) << 4)));
#pragma unroll
          for (int ut = 0; ut < 2; ++ut) {
            acc[0][ut] = __builtin_amdgcn_mfma_f32_16x16x32_bf16(a0, barr[ut][kt], acc[0][ut], 0, 0, 0);
            acc[1][ut] = __builtin_amdgcn_mfma_f32_16x16x32_bf16(a1, barr[ut][kt], acc[1][ut], 0, 0, 0);
          }
        }
#pragma unroll
        for (int q = 0; q < 4; ++q) {
          gh[gate][sig][brow + q][ucol]           = acc[0][0][q];
          gh[gate][sig][brow + q][ucol + 16]      = acc[0][1][q];
          gh[gate][sig][16 + brow + q][ucol]      = acc[1][0][q];
          gh[gate][sig][16 + brow + q][ucol + 16] = acc[1][1][q];
        }
      }
      __syncthreads();   // gh ready
#pragma unroll
      for (int s = 0; s < 3; ++s) {
        if (s == 2 && !act2) break;
        int b = b_[s], u = u_[s];
        float gr = s == 0 ? gr0 : s == 1 ? gr1 : gr2;
        float gz = s == 0 ? gz0 : s == 1 ? gz1 : gz2;
        float gn = s == 0 ? gn0 : s == 1 ? gn1 : gn2;
        float hr = gh[0][0][b][u] + gh[0][1][b][u] + bb0[s];
        float hz = gh[1][0][b][u] + gh[1][1][b][u] + bb1[s];
        float hn = gh[2][0][b][u] + gh[2][1][b][u] + bb2[s];
        float r = 1.f / (1.f + __builtin_amdgcn_exp2f(K1 * (gr + hr)));
        float z = 1.f / (1.f + __builtin_amdgcn_exp2f(K1 * (gz + hz)));
        float x = gn + r * hn;
        float th = 1.f - 2.f / (1.f + __builtin_amdgcn_exp2f(K2 * x));
        float hnew = th + z * (hprev[s] - th);
        hprev[s] = hnew;
        unsigned hb = (unsigned)f2bf(hnew);
        u16* hp = s == 0 ? hs0 : s == 1 ? hs1 : hs2;
        asm volatile("global_store_short %0, %1, off sc0 sc1"
                     :: "v"(hp), "v"(hb) : "memory");
      }
      hs0 += 16384; hs1 += 16384; if (act2) hs2 += 16384;
      asm volatile("s_waitcnt vmcnt(0)" ::: "memory");
      __syncthreads();   // all HS(t) at LLC
      if (tid == 704) {
        unsigned ph = (unsigned)(t + 1);
        asm volatile("global_store_dword %0, %1, off sc0 sc1\n\ts_waitcnt vmcnt(0)"
                     :: "v"(flags + g * 16), "v"(ph) : "memory");
      }
    }
#pragma unroll
    for (int s = 0; s < 3; ++s) {
      if (s == 2 && !act2) break;
      outH[b_[s] * 512 + j0 + u_[s]] = hprev[s];
    }
    return;
  }

  // ================= projection path =================
  int x = xcd_s, Lx = lead_s;
  int nchunk = (x == Lx) ? 26 : 32;            // 26 + 7*32 = 250
  int nlo = 0;
  for (int q = 0; q < x; ++q) nlo += (q == Lx) ? 26 : 32;
  int grp = wave >> 2, wv = wave & 3;
  int wr = wv >> 1, wc = wv & 1;
  u16* At = (u16*)(arena + grp * 32768);       // 2 bufs x 4096 u16 (A then B)
  u16* Bt = At + 8192;
  const long k16 = 16L * 512;
  for (;;) {
    if (tid == 0) tick_s = (int)atomicAdd(&evars[16 + x], 1u);
    __syncthreads();
    int e = tick_s;
    __syncthreads();   // tick_s stable before next claim overwrites
    if (e >= nchunk) break;
    int nt = nlo + e;
    // ---- cast this nt's Wout panel f32 -> bf16 (exclusive ownership) ----
    {
      const float4* wsrc = reinterpret_cast<const float4*>(WoutF) + (long)nt * 16384;
      u16x4v* wdst = reinterpret_cast<u16x4v*>(WoutB) + (long)nt * 16384;
      for (int idx = tid; idx < 16384; idx += 768) {
        float4 v = wsrc[idx];
        u16x4v o; o.x = f2bf(v.x); o.y = f2bf(v.y); o.z = f2bf(v.z); o.w = f2bf(v.w);
        wdst[idx] = o;
      }
    }
    __syncthreads();   // panel in L2 before staging reads
    // ---- 16 mt-tiles in 6 rounds of 3 (one per group), gated on GRU progress ----
    for (int r = 0; r < 6; ++r) {
      int mt0 = r * 3;
      int lastmt = (mt0 + 2 > 15) ? 15 : mt0 + 2;
      unsigned need = 4u * (unsigned)(lastmt + 1);
      if (wave == 0) {
        const unsigned* fp = flags + (lane & 7) * 16;
        unsigned v; int it = 0;
        for (;;) {
          asm volatile("global_load_dword %0, %1, off sc0 sc1\n\ts_waitcnt vmcnt(0)"
                       : "=v"(v) : "v"(fp) : "memory");
          if (__all((int)(v >= need)) || ++it > (1 << 22)) break;
          asm volatile("s_sleep 16");
        }
      }
      __syncthreads();
      int mt = mt0 + grp;
      bool active = mt <= 15;
      f32x4 acc[4][4] = {};
      const u16* ga = HS + (long)(mt * 128 + wv * 32 + (lane >> 2)) * 512 + ((lane & 3) << 3);
      const u16* gb = WoutB + (long)(nt * 128 + wv * 32 + (lane >> 2)) * 512 + ((lane & 3) << 3);
      if (active) {
        gload16(ga, &At[wv * 1024]);        gload16(ga + k16, &At[wv * 1024 + 512]);
        gload16(gb, &Bt[wv * 1024]);        gload16(gb + k16, &Bt[wv * 1024 + 512]);
      }
      asm volatile("s_waitcnt vmcnt(0)" ::: "memory");
      __syncthreads();
      int cur = 0;
      for (int k0 = 0; k0 < 512; k0 += 32) {
        if (active && k0 + 32 < 512) {
          int nb = cur ^ 1;
          gload16(ga + k0 + 32, &At[nb * 4096 + wv * 1024]);
          gload16(ga + k16 + k0 + 32, &At[nb * 4096 + wv * 1024 + 512]);
          gload16(gb + k0 + 32, &Bt[nb * 4096 + wv * 1024]);
          gload16(gb + k16 + k0 + 32, &Bt[nb * 4096 + wv * 1024 + 512]);
        }
        if (active) {
          bf16x8 af[4], bfr[4];
#pragma unroll
          for (int mi = 0; mi < 4; ++mi)
            af[mi] = *reinterpret_cast<const bf16x8*>(
                &At[cur * 4096 + (wr * 64 + mi * 16 + (lane & 15)) * 32 + ((lane >> 4) << 3)]);
#pragma unroll
          for (int ni = 0; ni < 4; ++ni)
            bfr[ni] = *reinterpret_cast<const bf16x8*>(
                &Bt[cur * 4096 + (wc * 64 + ni * 16 + (lane & 15)) * 32 + ((lane >> 4) << 3)]);
#pragma unroll
          for (int mi = 0; mi < 4; ++mi)
#pragma unroll
            for (int ni = 0; ni < 4; ++ni)
              acc[mi][ni] = __builtin_amdgcn_mfma_f32_16x16x32_bf16(af[mi], bfr[ni], acc[mi][ni], 0, 0, 0);
        }
        asm volatile("s_waitcnt vmcnt(0)" ::: "memory");
        __syncthreads();
        cur ^= 1;
      }
      if (active) {
        int rb = mt * 128 + wr * 64 + ((lane >> 4) << 2);
        int cb = nt * 128 + wc * 64 + (lane & 15);
#pragma unroll
        for (int mi = 0; mi < 4; ++mi)
#pragma unroll
          for (int ni = 0; ni < 4; ++ni) {
            int col = cb + ni * 16;
            float bv = bout[col];
#pragma unroll
            for (int q = 0; q < 4; ++q) {
              int rr = rb + mi * 16 + q;                   // HS row = t*32 + b
              long orow = (long)(rr & 31) * 64 + (rr >> 5); // out row = b*64 + t
              LG[orow * LDC2 + col] = f2bf(acc[mi][ni][q] + bv);
            }
          }
      }
      __syncthreads();   // LDS safe for next round
    }
  }
}

// ---------------- log_softmax: bf16 logits (aliased in d_out row slot) -> f32 ----------------
extern "C" __global__ void __launch_bounds__(512)
k_lsm_b(const u16* __restrict__ LGbase, float* __restrict__ P) {
  extern __shared__ u16 srb[];
  __shared__ float red[8];
  const u16* LG = LGbase + (long)blockIdx.x * LDC2;
  float* out = P + (long)blockIdx.x * 32000;
  int tid = threadIdx.x, wave = tid >> 6, lane = tid & 63;
  float mx = -INFINITY;
  for (int i = tid; i < 4000; i += 512) {
    u16x8v v = reinterpret_cast<const u16x8v*>(LG)[i];
    reinterpret_cast<u16x8v*>(srb)[i] = v;
#pragma unroll
    for (int e = 0; e < 8; ++e) mx = fmaxf(mx, bf2f(v[e]));
  }
#pragma unroll
  for (int off = 32; off; off >>= 1) mx = fmaxf(mx, __shfl_down(mx, off, 64));
  if (lane == 0) red[wave] = mx;
  __syncthreads();
  if (tid == 0) {
    float m = red[0];
#pragma unroll
    for (int w = 1; w < 8; ++w) m = fmaxf(m, red[w]);
    red[0] = m;
  }
  __syncthreads();
  mx = red[0];
  __syncthreads();
  float sm = 0.f;
  for (int i = tid; i < 4000; i += 512) {
    u16x8v v = reinterpret_cast<const u16x8v*>(srb)[i];
#pragma unroll
    for (int e = 0; e < 8; ++e) sm += __expf(bf2f(v[e]) - mx);
  }
#pragma unroll
  for (int off = 32; off; off >>= 1) sm += __shfl_down(sm, off, 64);
  if (lane == 0) red[wave] = sm;
  __syncthreads();
  if (tid == 0) {
    float s = 0.f;
#pragma unroll
    for (int w = 0; w < 8; ++w) s += red[w];
    red[0] = mx + __logf(s);
  }
  __syncthreads();
  float L = red[0];
  for (int i = tid; i < 4000; i += 512) {
    u16x8v v = reinterpret_cast<const u16x8v*>(srb)[i];
    float4 o1, o2;
    o1.x = bf2f(v[0]) - L; o1.y = bf2f(v[1]) - L; o1.z = bf2f(v[2]) - L; o1.w = bf2f(v[3]) - L;
    o2.x = bf2f(v[4]) - L; o2.y = bf2f(v[5]) - L; o2.z = bf2f(v[6]) - L; o2.w = bf2f(v[7]) - L;
    reinterpret_cast<float4*>(out + (long)i * 8)[0] = o1;
    reinterpret_cast<float4*>(out + (long)i * 8)[1] = o2;
  }
}

extern "C" void kernel_launch(void* const* d_in, const int* in_sizes, int n_in,
                              void* d_out, int out_size, void* d_ws, size_t ws_size,
                              hipStream_t stream) {
  (void)in_sizes; (void)n_in; (void)out_size;
  const float* enc_hid = (const float*)d_in[1];
  const int*   tgt     = (const int*)d_in[2];
  const float* emb     = (const float*)d_in[3];
  const float* W_ih    = (const float*)d_in[4];
  const float* W_hh    = (const float*)d_in[5];
  const float* b_ih    = (const float*)d_in[6];
  const float* b_hh    = (const float*)d_in[7];
  const float* W_out   = (const float*)d_in[8];
  const float* b_out   = (const float*)d_in[9];
  float* out = (float*)d_out;
  char* ws = (char*)d_ws;
  if (ws_size < (size_t)WS_NEED) return;

  u16* X        = (u16*)(ws + OFF_X);
  u16* Wih      = (u16*)(ws + OFF_WIH);
  u16* Wout     = (u16*)(ws + OFF_WOUT);
  float* gi     = (float*)(ws + OFF_GI);
  u16* HS       = (u16*)(ws + OFF_HS);
  unsigned* flg = (unsigned*)(ws + OFF_FLG);
  unsigned* ev  = (unsigned*)(ws + OFF_EV);
  u16* LG       = (u16*)d_out;   // bf16 logits: row r in first half of row r's f32 slot

  hipFuncSetAttribute(reinterpret_cast<const void*>(k_mega2),
                      hipFuncAttributeMaxDynamicSharedMemorySize, 98304);
  hipFuncSetAttribute(reinterpret_cast<const void*>(k_lsm_b),
                      hipFuncAttributeMaxDynamicSharedMemorySize, 65536);

  k_cast<<<96, 256, 0, stream>>>(W_ih, Wih, 1536 * 256 / 4);
  k_embed<<<256, 256, 0, stream>>>(emb, tgt, X);
  k_init<<<1, 256, 0, stream>>>(flg, ev);
  k_gemm_gi<<<(1536 / 128) * (2048 / 128), 256, 0, stream>>>(
      X, Wih, b_ih, gi, 2048, 1536, 256);
  k_mega2<<<256, 768, 98304, stream>>>(gi, W_hh, b_hh, enc_hid, HS, out + BTV,
                                       flg, ev, W_out, Wout, b_out, LG);
  k_lsm_b<<<2048, 512, 64000, stream>>>(LG, out);
}

// Round 16
// 417.957 us; speedup vs baseline: 1.3031x; 1.3031x over previous
//
#include <hip/hip_runtime.h>
#include <hip/hip_bf16.h>
#include <math.h>

// GRU decoder: k_pre (embed+relu | W_ih cast | W_hh cast | flag init) -> gi GEMM ->
// hidden-split GRU (8 elected blocks; 56 idle blocks cast W_out under the
// recurrence) -> vocab projection (XCD-affine, bf16 logits in d_out) -> log_softmax.

typedef __bf16 bf16x8 __attribute__((ext_vector_type(8)));
typedef float  f32x4  __attribute__((ext_vector_type(4)));
typedef unsigned short u16;
typedef u16 u16x8v __attribute__((ext_vector_type(8)));
typedef u16 u16x4v __attribute__((ext_vector_type(4)));

#define BTV (32L * 64 * 32000)
#define LDC2 64000L   // bf16 logit row stride inside d_out (half of a 128000B f32 row slot)

// ---- ws layout (bytes) ----
#define OFF_X    (0L)
#define SZ_X     (2048L * 256 * 2)
#define OFF_WIH  (OFF_X + SZ_X)
#define SZ_WIH   (1536L * 256 * 2)
#define OFF_WHH  (OFF_WIH + SZ_WIH)
#define SZ_WHH   (1536L * 512 * 2)
#define OFF_WOUT (OFF_WHH + SZ_WHH)
#define SZ_WOUT  (32000L * 512 * 2)
#define OFF_GI   (OFF_WOUT + SZ_WOUT)
#define SZ_GI    (2048L * 1536 * 4)
#define OFF_HS   (OFF_GI + SZ_GI)
#define SZ_HS    (2048L * 512 * 2)
#define OFF_FLG  (OFF_HS + SZ_HS)
#define SZ_FLG   (1024L)
#define OFF_EV   (OFF_FLG + SZ_FLG)
#define SZ_EV    (64L)
#define WS_NEED  (OFF_EV + SZ_EV)

__device__ __forceinline__ u16 f2bf(float f) {
  union { float f; unsigned u; } a; a.f = f;
  unsigned r = a.u + 0x7fffu + ((a.u >> 16) & 1u);
  return (u16)(r >> 16);
}

__device__ __forceinline__ float bf2f(u16 u) {
  union { unsigned u; float f; } a; a.u = ((unsigned)u) << 16;
  return a.f;
}

__device__ __forceinline__ void gload16(const void* g, void* l) {
  __builtin_amdgcn_global_load_lds(
      (const __attribute__((address_space(1))) unsigned int*)g,
      (__attribute__((address_space(3))) unsigned int*)l, 16, 0, 0);
}

// ---- fused pre-pass: embed+relu (blk 0-255) | init (blk 256) | W_ih cast
// (blk 256-351) | W_hh cast (blk 352-543) ----
extern "C" __global__ void k_pre(const float* __restrict__ emb, const int* __restrict__ tgt,
                                 u16* __restrict__ X, const float* __restrict__ Wihf,
                                 u16* __restrict__ Wih, const float* __restrict__ Whhf,
                                 u16* __restrict__ Whh, unsigned* flags, unsigned* evars) {
  int bid = blockIdx.x, tid = threadIdx.x;
  if (bid < 256) {
    int idx = bid * 256 + tid;
    int row = idx >> 5;
    int c8  = (idx & 31) << 3;
    int t = row >> 5, b = row & 31;
    int token = (t == 0) ? 0 : tgt[b * 64 + t - 1];
    const float* e = emb + (long)token * 256 + c8;
    u16x8v o;
#pragma unroll
    for (int i = 0; i < 8; ++i) { float v = e[i]; o[i] = f2bf(v > 0.f ? v : 0.f); }
    *reinterpret_cast<u16x8v*>(X + (long)row * 256 + c8) = o;
    return;
  }
  if (bid == 256) {
    if (tid < 256) {
      unsigned z = 0u;
      asm volatile("global_store_dword %0, %1, off sc0 sc1"
                   :: "v"(flags + tid), "v"(z) : "memory");
    }
    if (tid < 12) atomicExch(&evars[tid], tid == 8 ? 0xFFFFFFFFu : 0u);
  }
  if (bid < 352) {
    for (int i = (bid - 256) * 256 + tid; i < 98304; i += 96 * 256) {
      float4 v = reinterpret_cast<const float4*>(Wihf)[i];
      u16x4v o; o.x = f2bf(v.x); o.y = f2bf(v.y); o.z = f2bf(v.z); o.w = f2bf(v.w);
      reinterpret_cast<u16x4v*>(Wih)[i] = o;
    }
    return;
  }
  {
    int i = (bid - 352) * 256 + tid;   // 192 blocks, 196608 float4, 4 each
    for (int idx = i; idx < 196608; idx += 192 * 256) {
      float4 v = reinterpret_cast<const float4*>(Whhf)[idx];
      u16x4v o; o.x = f2bf(v.x); o.y = f2bf(v.y); o.z = f2bf(v.z); o.w = f2bf(v.w);
      reinterpret_cast<u16x4v*>(Whh)[idx] = o;
    }
  }
}

// ---------------- bf16 MFMA GEMM, C = A*B^T + bias, 2-phase dbuf, XCD-affine ----------------
template <bool BF16OUT>
__global__ void __launch_bounds__(256)
k_gemm_t(const u16* __restrict__ A, const u16* __restrict__ B,
         const float* __restrict__ bias, float* __restrict__ C,
         u16* __restrict__ C2, int M, int N, int K, long ldc2) {
  __shared__ u16 At[2][4096];
  __shared__ u16 Bt[2][4096];
  int mt = M >> 7;
  int i = blockIdx.x;
  int j = (i & 7) * ((int)gridDim.x >> 3) + (i >> 3);
  int bn = j / mt, bm = j % mt;
  int tid = threadIdx.x, wave = tid >> 6, lane = tid & 63;
  int wr = wave >> 1, wc = wave & 1;
  f32x4 acc[4][4] = {};
  const u16* ga = A + (long)(bm * 128 + wave * 32 + (lane >> 2)) * K + ((lane & 3) << 3);
  const u16* gb = B + (long)(bn * 128 + wave * 32 + (lane >> 2)) * K + ((lane & 3) << 3);
  long k16 = 16L * K;
  {
    u16* la0 = &At[0][wave * 1024]; u16* lb0 = &Bt[0][wave * 1024];
    gload16(ga, la0); gload16(ga + k16, la0 + 512);
    gload16(gb, lb0); gload16(gb + k16, lb0 + 512);
  }
  asm volatile("s_waitcnt vmcnt(0)" ::: "memory");
  __syncthreads();
  int cur = 0;
  for (int k0 = 0; k0 < K; k0 += 32) {
    if (k0 + 32 < K) {
      int nb = cur ^ 1;
      u16* la0 = &At[nb][wave * 1024]; u16* lb0 = &Bt[nb][wave * 1024];
      gload16(ga + k0 + 32, la0); gload16(ga + k16 + k0 + 32, la0 + 512);
      gload16(gb + k0 + 32, lb0); gload16(gb + k16 + k0 + 32, lb0 + 512);
    }
    bf16x8 af[4], bfr[4];
#pragma unroll
    for (int mi = 0; mi < 4; ++mi)
      af[mi] = *reinterpret_cast<const bf16x8*>(
          &At[cur][(wr * 64 + mi * 16 + (lane & 15)) * 32 + ((lane >> 4) << 3)]);
#pragma unroll
    for (int ni = 0; ni < 4; ++ni)
      bfr[ni] = *reinterpret_cast<const bf16x8*>(
          &Bt[cur][(wc * 64 + ni * 16 + (lane & 15)) * 32 + ((lane >> 4) << 3)]);
#pragma unroll
    for (int mi = 0; mi < 4; ++mi)
#pragma unroll
      for (int ni = 0; ni < 4; ++ni)
        acc[mi][ni] = __builtin_amdgcn_mfma_f32_16x16x32_bf16(af[mi], bfr[ni], acc[mi][ni], 0, 0, 0);
    asm volatile("s_waitcnt vmcnt(0)" ::: "memory");
    __syncthreads();
    cur ^= 1;
  }
  int rb = bm * 128 + wr * 64 + ((lane >> 4) << 2);
  int cb = bn * 128 + wc * 64 + (lane & 15);
#pragma unroll
  for (int mi = 0; mi < 4; ++mi)
#pragma unroll
    for (int ni = 0; ni < 4; ++ni) {
      int col = cb + ni * 16;
      float bv = bias[col];
#pragma unroll
      for (int q = 0; q < 4; ++q) {
        int rr = rb + mi * 16 + q;
        if (BF16OUT) C2[(long)rr * ldc2 + col] = f2bf(acc[mi][ni][q] + bv);
        else         C[(long)rr * N + col] = acc[mi][ni][q] + bv;
      }
    }
}

// ---------------- hidden-split GRU (R7 structure) + idle-block W_out cast ----------------
extern "C" __global__ void __launch_bounds__(768, 1)
k_gru9(const float* __restrict__ gi, const u16* __restrict__ Whh,
       const float* __restrict__ bhh, const float* __restrict__ eh,
       u16* __restrict__ HS, float* __restrict__ outH,
       unsigned* flags, unsigned* evars,
       const float* __restrict__ Wof, u16* __restrict__ WoutB) {
  __shared__ u16 Ah[32 * 512];
  __shared__ float gh[3][2][32][66];
  __shared__ int role_s;
  __shared__ int tick_s;
  int tid = threadIdx.x, wave = tid >> 6, lane = tid & 63;
  if (tid == 0) {
    unsigned xcc;
    asm volatile("s_getreg_b32 %0, hwreg(20, 0, 32)" : "=s"(xcc));
    xcc &= 7u;
    unsigned arr = atomicAdd(&evars[xcc], 1u);
    if (arr == 7u) atomicCAS(&evars[8], 0xFFFFFFFFu, xcc);
    unsigned L = 0xFFFFFFFFu;
    for (int it = 0; it < (1 << 24) && L == 0xFFFFFFFFu; ++it) {
      asm volatile("global_load_dword %0, %1, off sc0 sc1\n\ts_waitcnt vmcnt(0)"
                   : "=v"(L) : "v"(evars + 8) : "memory");
    }
    int role = -1;
    if (L == xcc) {
      unsigned c = atomicAdd(&evars[9], 1u);
      if (c < 8u) role = (int)c;
    }
    role_s = role;
  }
  __syncthreads();
  int g = role_s;
  if (g < 0) {
    if (tid == 0) tick_s = (int)atomicAdd(&evars[11], 1u);
    __syncthreads();
    long c = (long)tick_s;
    const float4* src = reinterpret_cast<const float4*>(Wof);
    u16x4v* dst = reinterpret_cast<u16x4v*>(WoutB);
    for (long idx = c * 768 + tid; idx < 4096000L; idx += 56L * 768) {
      float4 v = src[idx];
      u16x4v o; o.x = f2bf(v.x); o.y = f2bf(v.y); o.z = f2bf(v.z); o.w = f2bf(v.w);
      dst[idx] = o;
    }
    return;
  }
  int j0 = g * 64;
  int gate = wave >> 2, uh = (wave >> 1) & 1, sig = wave & 1;
  bf16x8 barr[2][8];
  {
    const u16* wbase = Whh + (long)(gate * 512 + j0 + uh * 32) * 512 + sig * 256;
#pragma unroll
    for (int ut = 0; ut < 2; ++ut)
#pragma unroll
      for (int kt = 0; kt < 8; ++kt)
        barr[ut][kt] = *reinterpret_cast<const bf16x8*>(
            wbase + (long)(ut * 16 + (lane & 15)) * 512 + kt * 32 + ((lane >> 4) << 3));
  }
  bool act2 = tid < 512;
  float hprev[3] = {}, bb0[3] = {}, bb1[3] = {}, bb2[3] = {};
  const float* gp0; const float* gp1; const float* gp2 = nullptr;
  u16* hs0; u16* hs1; u16* hs2 = nullptr;
  int b_[3], u_[3];
#pragma unroll
  for (int s = 0; s < 3; ++s) {
    int o = s * 768 + tid;
    if (o < 2048) {
      int b = o >> 6, u = o & 63, j = j0 + u;
      b_[s] = b; u_[s] = u;
      hprev[s] = eh[b * 512 + j];
      bb0[s] = bhh[j]; bb1[s] = bhh[512 + j]; bb2[s] = bhh[1024 + j];
    } else { b_[s] = 0; u_[s] = 0; }
  }
  gp0 = gi + (long)b_[0] * 1536 + j0 + u_[0];
  gp1 = gi + (long)b_[1] * 1536 + j0 + u_[1];
  if (act2) gp2 = gi + (long)b_[2] * 1536 + j0 + u_[2];
  hs0 = HS + ((long)b_[0] * 64) * 512 + j0 + u_[0];
  hs1 = HS + ((long)b_[1] * 64) * 512 + j0 + u_[1];
  if (act2) hs2 = HS + ((long)b_[2] * 64) * 512 + j0 + u_[2];
  const char* sp0 = nullptr; const char* sp1 = nullptr;
  const char* sp2 = nullptr; const char* sp3 = nullptr;
  char* ld0 = nullptr; char* ld1 = nullptr; char* ld2 = nullptr; char* ld3 = nullptr;
  if (tid < 512) {
#pragma unroll
    for (int l = 0; l < 4; ++l) {
      int n = l * 512 + tid;
      int row = n >> 6, i = n & 63;
      const char* sp = (const char*)HS + (long)row * 65536 + i * 16 - 1024;
      char* ld = (char*)Ah + row * 1024 + ((i * 16) ^ ((row & 7) << 4));
      if (l == 0) { sp0 = sp; ld0 = ld; } else if (l == 1) { sp1 = sp; ld1 = ld; }
      else if (l == 2) { sp2 = sp; ld2 = ld; } else { sp3 = sp; ld3 = ld; }
    }
#pragma unroll
    for (int l = 0; l < 4; ++l) {
      int n = l * 512 + tid;
      int row = n >> 6, i = n & 63;
      const float* p = eh + row * 512 + i * 8;
      float4 aa = *reinterpret_cast<const float4*>(p);
      float4 bb = *reinterpret_cast<const float4*>(p + 4);
      u16x8v o8;
      o8[0] = f2bf(aa.x); o8[1] = f2bf(aa.y); o8[2] = f2bf(aa.z); o8[3] = f2bf(aa.w);
      o8[4] = f2bf(bb.x); o8[5] = f2bf(bb.y); o8[6] = f2bf(bb.z); o8[7] = f2bf(bb.w);
      *reinterpret_cast<u16x8v*>((char*)Ah + row * 1024 + ((i * 16) ^ ((row & 7) << 4))) = o8;
    }
  }
  const float K1 = -1.44269504f, K2 = 2.88539009f;
  for (int t = 0; t < 64; ++t) {
    float gr0 = gp0[0], gz0 = gp0[512], gn0 = gp0[1024];
    float gr1 = gp1[0], gz1 = gp1[512], gn1 = gp1[1024];
    float gr2 = 0.f, gz2 = 0.f, gn2 = 0.f;
    if (act2) { gr2 = gp2[0]; gz2 = gp2[512]; gn2 = gp2[1024]; }
    gp0 += 49152; gp1 += 49152; if (act2) gp2 += 49152;
    if (t) {
      if (wave == 0) {
        const unsigned* fp = flags + (lane & 7) * 16;
        unsigned v;
        do {
          asm volatile("global_load_dword %0, %1, off sc0 sc1\n\ts_waitcnt vmcnt(0)"
                       : "=v"(v) : "v"(fp) : "memory");
        } while (!__all((int)(v >= (unsigned)t)));
      }
      __syncthreads();
      if (tid < 512) {
        f32x4 d0, d1, d2, d3;
        asm volatile(
            "global_load_dwordx4 %0, %4, off sc0\n\t"
            "global_load_dwordx4 %1, %5, off sc0\n\t"
            "global_load_dwordx4 %2, %6, off sc0\n\t"
            "global_load_dwordx4 %3, %7, off sc0\n\t"
            "s_waitcnt vmcnt(0)"
            : "=v"(d0), "=v"(d1), "=v"(d2), "=v"(d3)
            : "v"(sp0), "v"(sp1), "v"(sp2), "v"(sp3)
            : "memory");
        *reinterpret_cast<f32x4*>(ld0) = d0;
        *reinterpret_cast<f32x4*>(ld1) = d1;
        *reinterpret_cast<f32x4*>(ld2) = d2;
        *reinterpret_cast<f32x4*>(ld3) = d3;
      }
    }
    if (tid < 512) { sp0 += 1024; sp1 += 1024; sp2 += 1024; sp3 += 1024; }
    __syncthreads();
    f32x4 acc[2][2] = {};
    int r15 = lane & 15;
    int cbyte = sig * 512 + ((lane >> 4) << 4);
#pragma unroll
    for (int kt = 0; kt < 8; ++kt) {
      bf16x8 a0 = *reinterpret_cast<const bf16x8*>(
          (const char*)Ah + r15 * 1024 + ((kt * 64 + cbyte) ^ ((r15 & 7) << 4)));
      bf16x8 a1 = *reinterpret_cast<const bf16x8*>(
          (const char*)Ah + (16 + r15) * 1024 + ((kt * 64 + cbyte) ^ ((r15 & 7) << 4)));
#pragma unroll
      for (int ut = 0; ut < 2; ++ut) {
        acc[0][ut] = __builtin_amdgcn_mfma_f32_16x16x32_bf16(a0, barr[ut][kt], acc[0][ut], 0, 0, 0);
        acc[1][ut] = __builtin_amdgcn_mfma_f32_16x16x32_bf16(a1, barr[ut][kt], acc[1][ut], 0, 0, 0);
      }
    }
    {
      int ucol = uh * 32 + r15;
      int brow = (lane >> 4) << 2;
#pragma unroll
      for (int q = 0; q < 4; ++q) {
        gh[gate][sig][brow + q][ucol]           = acc[0][0][q];
        gh[gate][sig][brow + q][ucol + 16]      = acc[0][1][q];
        gh[gate][sig][16 + brow + q][ucol]      = acc[1][0][q];
        gh[gate][sig][16 + brow + q][ucol + 16] = acc[1][1][q];
      }
    }
    __syncthreads();
#pragma unroll
    for (int s = 0; s < 3; ++s) {
      if (s == 2 && !act2) break;
      int b = b_[s], u = u_[s];
      float gr = s == 0 ? gr0 : s == 1 ? gr1 : gr2;
      float gz = s == 0 ? gz0 : s == 1 ? gz1 : gz2;
      float gn = s == 0 ? gn0 : s == 1 ? gn1 : gn2;
      float hr = gh[0][0][b][u] + gh[0][1][b][u] + bb0[s];
      float hz = gh[1][0][b][u] + gh[1][1][b][u] + bb1[s];
      float hn = gh[2][0][b][u] + gh[2][1][b][u] + bb2[s];
      float r = 1.f / (1.f + __builtin_amdgcn_exp2f(K1 * (gr + hr)));
      float z = 1.f / (1.f + __builtin_amdgcn_exp2f(K1 * (gz + hz)));
      float x = gn + r * hn;
      float th = 1.f - 2.f / (1.f + __builtin_amdgcn_exp2f(K2 * x));
      float hnew = th + z * (hprev[s] - th);
      hprev[s] = hnew;
      unsigned hb = (unsigned)f2bf(hnew);
      u16* hp = s == 0 ? hs0 : s == 1 ? hs1 : hs2;
      asm volatile("global_store_short %0, %1, off sc0"
                   :: "v"(hp), "v"(hb) : "memory");
    }
    hs0 += 512; hs1 += 512; if (act2) hs2 += 512;
    asm volatile("s_waitcnt vmcnt(0)" ::: "memory");
    __syncthreads();
    // flag store on wave 11, no ack wait: wave 0's next poll must not eat the
    // store's LLC round trip (release order ensured by the HS drain above)
    if (tid == 704) {
      unsigned ph = (unsigned)(t + 1);
      asm volatile("global_store_dword %0, %1, off sc0 sc1"
                   :: "v"(flags + g * 16), "v"(ph) : "memory");
    }
  }
#pragma unroll
  for (int s = 0; s < 3; ++s) {
    if (s == 2 && !act2) break;
    outH[b_[s] * 512 + j0 + u_[s]] = hprev[s];
  }
}

// ---------------- log_softmax: bf16 logits (aliased in d_out row slot) -> f32 ----------------
extern "C" __global__ void __launch_bounds__(512)
k_lsm_b(const u16* __restrict__ LGbase, float* __restrict__ P) {
  extern __shared__ u16 srb[];
  __shared__ float red[8];
  const u16* LG = LGbase + (long)blockIdx.x * LDC2;
  float* out = P + (long)blockIdx.x * 32000;
  int tid = threadIdx.x, wave = tid >> 6, lane = tid & 63;
  float mx = -INFINITY;
  for (int i = tid; i < 4000; i += 512) {
    u16x8v v = reinterpret_cast<const u16x8v*>(LG)[i];
    reinterpret_cast<u16x8v*>(srb)[i] = v;
#pragma unroll
    for (int e = 0; e < 8; ++e) mx = fmaxf(mx, bf2f(v[e]));
  }
#pragma unroll
  for (int off = 32; off; off >>= 1) mx = fmaxf(mx, __shfl_down(mx, off, 64));
  if (lane == 0) red[wave] = mx;
  __syncthreads();
  if (tid == 0) {
    float m = red[0];
#pragma unroll
    for (int w = 1; w < 8; ++w) m = fmaxf(m, red[w]);
    red[0] = m;
  }
  __syncthreads();
  mx = red[0];
  __syncthreads();
  float sm = 0.f;
  for (int i = tid; i < 4000; i += 512) {
    u16x8v v = reinterpret_cast<const u16x8v*>(srb)[i];
#pragma unroll
    for (int e = 0; e < 8; ++e) sm += __expf(bf2f(v[e]) - mx);
  }
#pragma unroll
  for (int off = 32; off; off >>= 1) sm += __shfl_down(sm, off, 64);
  if (lane == 0) red[wave] = sm;
  __syncthreads();
  if (tid == 0) {
    float s = 0.f;
#pragma unroll
    for (int w = 0; w < 8; ++w) s += red[w];
    red[0] = mx + __logf(s);
  }
  __syncthreads();
  float L = red[0];
  for (int i = tid; i < 4000; i += 512) {
    u16x8v v = reinterpret_cast<const u16x8v*>(srb)[i];
    float4 o1, o2;
    o1.x = bf2f(v[0]) - L; o1.y = bf2f(v[1]) - L; o1.z = bf2f(v[2]) - L; o1.w = bf2f(v[3]) - L;
    o2.x = bf2f(v[4]) - L; o2.y = bf2f(v[5]) - L; o2.z = bf2f(v[6]) - L; o2.w = bf2f(v[7]) - L;
    reinterpret_cast<float4*>(out + (long)i * 8)[0] = o1;
    reinterpret_cast<float4*>(out + (long)i * 8)[1] = o2;
  }
}

extern "C" void kernel_launch(void* const* d_in, const int* in_sizes, int n_in,
                              void* d_out, int out_size, void* d_ws, size_t ws_size,
                              hipStream_t stream) {
  (void)in_sizes; (void)n_in; (void)out_size;
  const float* enc_hid = (const float*)d_in[1];
  const int*   tgt     = (const int*)d_in[2];
  const float* emb     = (const float*)d_in[3];
  const float* W_ih    = (const float*)d_in[4];
  const float* W_hh    = (const float*)d_in[5];
  const float* b_ih    = (const float*)d_in[6];
  const float* b_hh    = (const float*)d_in[7];
  const float* W_out   = (const float*)d_in[8];
  const float* b_out   = (const float*)d_in[9];
  float* out = (float*)d_out;
  char* ws = (char*)d_ws;
  if (ws_size < (size_t)WS_NEED) return;

  u16* X        = (u16*)(ws + OFF_X);
  u16* Wih      = (u16*)(ws + OFF_WIH);
  u16* Whh      = (u16*)(ws + OFF_WHH);
  u16* Wout     = (u16*)(ws + OFF_WOUT);
  float* gi     = (float*)(ws + OFF_GI);
  u16* HS       = (u16*)(ws + OFF_HS);
  unsigned* flg = (unsigned*)(ws + OFF_FLG);
  unsigned* ev  = (unsigned*)(ws + OFF_EV);
  u16* LG       = (u16*)d_out;   // bf16 logits: row r in first half of row r's f32 slot

  hipFuncSetAttribute(reinterpret_cast<const void*>(k_lsm_b),
                      hipFuncAttributeMaxDynamicSharedMemorySize, 65536);

  k_pre<<<544, 256, 0, stream>>>(emb, tgt, X, W_ih, Wih, W_hh, Whh, flg, ev);
  k_gemm_t<false><<<(1536 / 128) * (2048 / 128), 256, 0, stream>>>(
      X, Wih, b_ih, gi, nullptr, 2048, 1536, 256, 0);
  k_gru9<<<64, 768, 0, stream>>>(gi, Whh, b_hh, enc_hid, HS, out + BTV, flg, ev,
                                 W_out, Wout);
  k_gemm_t<true><<<(32000 / 128) * (2048 / 128), 256, 0, stream>>>(
      HS, Wout, b_out, nullptr, LG, 2048, 32000, 512, LDC2);
  k_lsm_b<<<2048, 512, 64000, stream>>>(LG, out);
}